// Round 4
// baseline (2349.061 us; speedup 1.0000x reference)
//
#include <hip/hip_runtime.h>

// cluster_layer: q[n,k] = (1/(1+||x_n - c_k||^2)) normalized over k  (alpha=1)
// N=1e6, D=64, K=20. HBM floor: 256 MB read + 80 MB write ~ 53 us (less w/ L3).
//
// R4 = R3 with the register budget fixed. R3 spilled (xv[4][8]=128 VGPR ->
// 2.6 GB scratch fetch, 1815 us). RPT=2, MC=8 keeps the live set ~130 VGPR:
//   xv 2x8 float4 = 64, acc 2x20 = 40, + addr/broadcast ~25.
// Full 128 B chunk per row loaded back-to-back (MSHR merge, R2 proved
// FETCH~=ideal) + clusters staged once into LDS, uniform ds_read_b128
// broadcast (R1 proved issue-efficient), amortized over 2 rows/thread.

#define NPTS 1000000
#define DIM  64
#define KCL  20
#define BLOCK 256
#define RPT  2            // rows per thread (register-budget bound)
#define MC   8            // float4 per chunk = 128 B = one full cache line
#define NCH  (DIM / 4 / MC)  // 2 chunks

__global__ __launch_bounds__(BLOCK, 3) void cluster_q_kernel(
    const float* __restrict__ x,
    const float* __restrict__ c,
    float* __restrict__ out)
{
    __shared__ float4 sC4[DIM / 4][KCL];   // transposed: [jc][k], 5 KB
    __shared__ float  sCsq[KCL];

    const int tid = threadIdx.x;
    for (int i = tid; i < KCL * (DIM / 4); i += BLOCK) {
        int k  = i / (DIM / 4);
        int jc = i % (DIM / 4);
        sC4[jc][k] = ((const float4*)c)[k * (DIM / 4) + jc];
    }
    __syncthreads();
    if (tid < KCL) {
        float s = 0.f;
        #pragma unroll
        for (int jc = 0; jc < DIM / 4; ++jc) {
            float4 v = sC4[jc][tid];
            s += v.x * v.x + v.y * v.y + v.z * v.z + v.w * v.w;
        }
        sCsq[tid] = s;
    }
    __syncthreads();

    int  row[RPT];
    bool valid[RPT];
    #pragma unroll
    for (int r = 0; r < RPT; ++r) {
        int rr = blockIdx.x * (BLOCK * RPT) + r * BLOCK + tid;
        valid[r] = (rr < NPTS);
        row[r] = valid[r] ? rr : (NPTS - 1);   // clamped duplicate load is harmless
    }

    float acc[RPT][KCL];
    float xsq[RPT];
    #pragma unroll
    for (int r = 0; r < RPT; ++r) {
        xsq[r] = 0.f;
        #pragma unroll
        for (int k = 0; k < KCL; ++k) acc[r][k] = 0.f;
    }

    const float4* __restrict__ x4 = (const float4*)x;

    #pragma unroll
    for (int ch = 0; ch < NCH; ++ch) {
        // 128 B per row, 8 back-to-back dwordx4 (line fully consumed in-flight)
        float4 xv[RPT][MC];
        #pragma unroll
        for (int r = 0; r < RPT; ++r)
            #pragma unroll
            for (int mc = 0; mc < MC; ++mc)
                xv[r][mc] = x4[(size_t)row[r] * (DIM / 4) + ch * MC + mc];

        #pragma unroll
        for (int r = 0; r < RPT; ++r)
            #pragma unroll
            for (int mc = 0; mc < MC; ++mc)
                xsq[r] += xv[r][mc].x * xv[r][mc].x + xv[r][mc].y * xv[r][mc].y
                        + xv[r][mc].z * xv[r][mc].z + xv[r][mc].w * xv[r][mc].w;

        #pragma unroll
        for (int mc = 0; mc < MC; ++mc) {
            const int jc = ch * MC + mc;
            #pragma unroll
            for (int k = 0; k < KCL; ++k) {
                const float4 cv = sC4[jc][k];   // uniform addr -> LDS broadcast
                #pragma unroll
                for (int r = 0; r < RPT; ++r)
                    acc[r][k] += xv[r][mc].x * cv.x + xv[r][mc].y * cv.y
                               + xv[r][mc].z * cv.z + xv[r][mc].w * cv.w;
            }
        }
    }

    // epilogue: d2 -> q -> normalize -> 5 aligned float4 stores per row
    #pragma unroll
    for (int r = 0; r < RPT; ++r) {
        if (!valid[r]) continue;
        float s = 0.f;
        float q[KCL];
        #pragma unroll
        for (int k = 0; k < KCL; ++k) {
            float d2 = xsq[r] + sCsq[k] - 2.0f * acc[r][k];
            float qq = __builtin_amdgcn_rcpf(1.0f + d2);   // v_rcp_f32, ~1 ulp
            q[k] = qq;
            s += qq;
        }
        const float inv = __builtin_amdgcn_rcpf(s);
        float4* o4 = (float4*)(out + (size_t)row[r] * KCL);
        #pragma unroll
        for (int k = 0; k < KCL; k += 4) {
            float4 v;
            v.x = q[k + 0] * inv;
            v.y = q[k + 1] * inv;
            v.z = q[k + 2] * inv;
            v.w = q[k + 3] * inv;
            o4[k / 4] = v;
        }
    }
}

extern "C" void kernel_launch(void* const* d_in, const int* in_sizes, int n_in,
                              void* d_out, int out_size, void* d_ws, size_t ws_size,
                              hipStream_t stream) {
    const float* x = (const float*)d_in[0];   // (N, D) fp32
    const float* c = (const float*)d_in[1];   // (K, D) fp32
    float* out = (float*)d_out;               // (N, K) fp32

    const int rows_per_block = BLOCK * RPT;                          // 512
    const int blocks = (NPTS + rows_per_block - 1) / rows_per_block; // 1954
    cluster_q_kernel<<<blocks, BLOCK, 0, stream>>>(x, c, out);
}